// Round 13
// baseline (239.479 us; speedup 1.0000x reference)
//
#include <hip/hip_runtime.h>
#include <hip/hip_bf16.h>

constexpr int kNN  = 10000;   // nodes
constexpr int kTT  = 12;      // timesteps
constexpr int kFIN = 32;      // input features
constexpr int kHH  = 64;      // hidden
constexpr int kH4  = 256;     // 4*hidden (gates)
constexpr int kOUT = 16;      // output features
constexpr int kNE  = 160000;  // edges
constexpr int kDB  = 256;     // detect blocks (pb[] partials, fallback path)

typedef _Float16 half8 __attribute__((ext_vector_type(8)));
typedef _Float16 half4 __attribute__((ext_vector_type(4)));
typedef _Float16 half2t __attribute__((ext_vector_type(2)));
typedef float floatx4 __attribute__((ext_vector_type(4)));

// Minimal-instruction activations: raw exp2 form, NO clamp needed —
// exp2(+inf)->inf, rcp(inf)->0 and exp2(-inf)->0 saturate both functions to
// the correct +-1 / {0,1} limits. sig: 4 VALU; tanh: 5 VALU.
__device__ __forceinline__ float rcp_fast(float x){ return __builtin_amdgcn_rcpf(x); }
__device__ __forceinline__ float sigf(float x){
  return rcp_fast(1.f + __builtin_amdgcn_exp2f(-1.44269504f*x));
}
__device__ __forceinline__ float tanh_fast(float x){
  return fmaf(-2.f, rcp_fast(__builtin_amdgcn_exp2f(2.88539008f*x) + 1.f), 1.f);
}

// Typed 2-element gather load -> float2 (k_agg reads fp32 x directly).
__device__ __forceinline__ float2 ld2f(const _Float16* p){
  half2t h = *(const half2t*)p; return make_float2((float)h[0], (float)h[1]);
}
__device__ __forceinline__ float2 ld2f(const float* p){
  return *(const float2*)p;
}

// FALLBACK int64-vs-int32 detection (odd words all zero <=> int64) + cnt
// zeroing. Only launched when in_sizes is ambiguous (normal path determines
// is64 on HOST from in_sizes[1] byte count).
__global__ void k_detect_zero(const int* __restrict__ ei, int* __restrict__ pb,
                              int* __restrict__ cnt){
  int a = 0;
  for (int i = blockIdx.x*256 + threadIdx.x; i < kNE; i += gridDim.x*256)
    a |= ei[2*i+1];
  unsigned long long m = __ballot(a != 0);
  __shared__ int bf;
  if (threadIdx.x == 0) bf = 0;
  __syncthreads();
  if (m && (threadIdx.x & 63) == 0) atomicOr(&bf, 1);
  __syncthreads();
  if (threadIdx.x == 0) pb[blockIdx.x] = bf;
  for (int i = blockIdx.x*256 + threadIdx.x; i < kNN; i += gridDim.x*256)
    cnt[i] = 0;
}

// Resolve is64: host-determined (is64h >= 0) or reduce pb[] (fallback).
__device__ __forceinline__ bool resolve_is64(int is64h, const int* __restrict__ pb,
                                             int* sflag){
  if (is64h >= 0) return is64h == 1;
  int v = 0;
  for (int i = threadIdx.x; i < kDB; i += 256) v |= pb[i];
  if (threadIdx.x == 0) *sflag = 0;
  __syncthreads();
  if (v) atomicOr(sflag, 1);
  __syncthreads();
  return (*sflag == 0);            // odd words all zero <=> int64 input
}

__global__ void k_deg(const int* __restrict__ ei, const int* __restrict__ pb,
                      int* __restrict__ cnt, int is64h){
  __shared__ int sflag;
  bool is64 = resolve_is64(is64h, pb, &sflag);
  int e = blockIdx.x*256 + threadIdx.x;
  if (e >= kNE) return;
  int c = is64 ? ei[2*(kNE+e)] : ei[kNE+e];
  atomicAdd(&cnt[c], 1);
}

// Exclusive scan of in-degree (single block, 1024 threads) + dis =
// rsqrt(deg+selfloop) + cur initialized to offs (scatter mutates cur only).
__global__ __launch_bounds__(1024) void k_scan(const int* __restrict__ cnt,
                       int* __restrict__ offs, int* __restrict__ cur,
                       float* __restrict__ dis){
  __shared__ int wsum[16];
  int tid = threadIdx.x;
  const int NT = 1024;
  const int CH = (kNN + NT - 1)/NT;
  int lo = tid*CH, hi = min(lo+CH, kNN);
  int s = 0;
  for (int i = lo; i < hi; ++i) s += cnt[i];
  int orig = s;
  int lane = tid & 63, wv = tid >> 6;
  #pragma unroll
  for (int d = 1; d < 64; d <<= 1){
    int v = __shfl_up(s, d, 64);
    if (lane >= d) s += v;
  }
  if (lane == 63) wsum[wv] = s;
  __syncthreads();
  int add = 0;
  for (int k2 = 0; k2 < wv; ++k2) add += wsum[k2];
  int run = s - orig + add;          // exclusive prefix for this thread's chunk
  for (int i = lo; i < hi; ++i){ offs[i] = run; cur[i] = run; run += cnt[i]; }
  if (hi == kNN) offs[kNN] = run;
  for (int i = tid; i < kNN; i += NT) dis[i] = rsqrtf((float)(cnt[i]+1));
}

// CSR scatter; packs (src, weight) into one int2 per edge. Slot comes
// straight from atomicAdd on cur (pre-initialized to offs by k_scan).
__global__ void k_scatter(const int* __restrict__ ei, const int* __restrict__ pb,
                          int* __restrict__ cur, const float* __restrict__ dis,
                          int2* __restrict__ edat, int is64h){
  __shared__ int sflag;
  bool is64 = resolve_is64(is64h, pb, &sflag);
  int e = blockIdx.x*256 + threadIdx.x;
  if (e >= kNE) return;
  int r = is64 ? ei[2*e]       : ei[e];
  int c = is64 ? ei[2*(kNE+e)] : ei[kNE+e];
  int p = atomicAdd(&cur[c], 1);
  edat[p] = make_int2(r, __float_as_int(dis[r]*dis[c]));
}

// GCN aggregation for F=32 (fp32 x input) — R5-verified wave structure
// (t-slab L2-resident, dual-node interleaved batch-4 walk). Unchanged.
template<int F, typename TIN>
__global__ __launch_bounds__(256) void k_agg(const TIN* __restrict__ hin,
                     _Float16* __restrict__ hout,
                     const float* __restrict__ dis,
                     const int* __restrict__ offs, const int2* __restrict__ edat){
  constexpr int LPF = F/2;            // lanes per timestep
  constexpr int TPW = 64/LPF;         // timesteps per wave
  constexpr int NP  = kNN/2;          // node pairs
  int wid = threadIdx.x >> 6, lane = threadIdx.x & 63;
  int gw = blockIdx.x*4 + wid;        // gw = tq*NP + np
  int tq = gw / NP, np = gw - tq*NP;
  int n0 = 2*np, n1 = n0 + 1;
  int fp = lane & (LPF-1), tsub = lane / LPF;
  int t = TPW*tq + tsub;
  const TIN* hb = hin + (size_t)t*kNN*F;
  float dA = dis[n0], dB = dis[n1];
  float2 svA = ld2f(&hb[(size_t)n0*F + 2*fp]);
  float2 svB = ld2f(&hb[(size_t)n1*F + 2*fp]);
  float a0 = dA*dA*svA.x, a1 = dA*dA*svA.y;
  float b0 = dB*dB*svB.x, b1 = dB*dB*svB.y;
  int eA  = __builtin_amdgcn_readfirstlane(offs[n0]);
  int eM  = __builtin_amdgcn_readfirstlane(offs[n1]);
  int e1B = __builtin_amdgcn_readfirstlane(offs[n1+1]);
  int e1A = eM, eB = eM;
  while (eA + 4 <= e1A && eB + 4 <= e1B){
    int2 dA4[4], dB4[4];
    #pragma unroll
    for (int u = 0; u < 4; ++u) dA4[u] = edat[eA+u];
    #pragma unroll
    for (int u = 0; u < 4; ++u) dB4[u] = edat[eB+u];
    float2 vA[4], vB[4];
    #pragma unroll
    for (int u = 0; u < 4; ++u) vA[u] = ld2f(&hb[(size_t)dA4[u].x*F + 2*fp]);
    #pragma unroll
    for (int u = 0; u < 4; ++u) vB[u] = ld2f(&hb[(size_t)dB4[u].x*F + 2*fp]);
    #pragma unroll
    for (int u = 0; u < 4; ++u){
      float wA = __int_as_float(dA4[u].y), wB = __int_as_float(dB4[u].y);
      a0 = fmaf(wA, vA[u].x, a0);
      a1 = fmaf(wA, vA[u].y, a1);
      b0 = fmaf(wB, vB[u].x, b0);
      b1 = fmaf(wB, vB[u].y, b1);
    }
    eA += 4; eB += 4;
  }
  // drain A
  for (; eA + 4 <= e1A; eA += 4){
    int2 d4[4];
    #pragma unroll
    for (int u = 0; u < 4; ++u) d4[u] = edat[eA+u];
    float2 vv[4];
    #pragma unroll
    for (int u = 0; u < 4; ++u) vv[u] = ld2f(&hb[(size_t)d4[u].x*F + 2*fp]);
    #pragma unroll
    for (int u = 0; u < 4; ++u){
      float wu = __int_as_float(d4[u].y);
      a0 = fmaf(wu, vv[u].x, a0);
      a1 = fmaf(wu, vv[u].y, a1);
    }
  }
  for (; eA < e1A; ++eA){
    int2 du = edat[eA];
    float wu = __int_as_float(du.y);
    float2 vu = ld2f(&hb[(size_t)du.x*F + 2*fp]);
    a0 = fmaf(wu, vu.x, a0);
    a1 = fmaf(wu, vu.y, a1);
  }
  // drain B
  for (; eB + 4 <= e1B; eB += 4){
    int2 d4[4];
    #pragma unroll
    for (int u = 0; u < 4; ++u) d4[u] = edat[eB+u];
    float2 vv[4];
    #pragma unroll
    for (int u = 0; u < 4; ++u) vv[u] = ld2f(&hb[(size_t)d4[u].x*F + 2*fp]);
    #pragma unroll
    for (int u = 0; u < 4; ++u){
      float wu = __int_as_float(d4[u].y);
      b0 = fmaf(wu, vv[u].x, b0);
      b1 = fmaf(wu, vv[u].y, b1);
    }
  }
  for (; eB < e1B; ++eB){
    int2 du = edat[eB];
    float wu = __int_as_float(du.y);
    float2 vu = ld2f(&hb[(size_t)du.x*F + 2*fp]);
    b0 = fmaf(wu, vu.x, b0);
    b1 = fmaf(wu, vu.y, b1);
  }
  half2t oA; oA[0] = (_Float16)a0; oA[1] = (_Float16)a1;
  *(half2t*)&hout[((size_t)t*kNN + n0)*F + 2*fp] = oA;
  half2t oB; oB[0] = (_Float16)b0; oB[1] = (_Float16)b1;
  *(half2t*)&hout[((size_t)t*kNN + n1)*F + 2*fp] = oB;
}

// GCN aggregation for F=64 (round-13): half4 gathers (8B/lane) — 16 lanes
// cover a 64-feat row, so a wave spans 4 timesteps (was 2) and the edge list
// is re-walked 3x instead of 6x; wave-wide gather instruction count HALVES
// at identical total bytes. Per-pass working set = 4 t-slabs = 5.1MB (same
// regime agg32 already runs in). 15000 waves (59/CU) — ample TLP.
__global__ __launch_bounds__(256) void k_agg64(const _Float16* __restrict__ hin,
                     _Float16* __restrict__ hout,
                     const float* __restrict__ dis,
                     const int* __restrict__ offs, const int2* __restrict__ edat){
  constexpr int F   = kHH;            // 64
  constexpr int NP  = kNN/2;          // node pairs
  int wid = threadIdx.x >> 6, lane = threadIdx.x & 63;
  int gw = blockIdx.x*4 + wid;        // gw = tq*NP + np, tq in [0,3)
  int tq = gw / NP, np = gw - tq*NP;
  int n0 = 2*np, n1 = n0 + 1;
  int fp = lane & 15, tsub = lane >> 4;
  int t = tq*4 + tsub;                // 4 t-slices per wave
  const _Float16* hb = hin + (size_t)t*kNN*F;
  float dA = dis[n0], dB = dis[n1];
  float wsA = dA*dA, wsB = dB*dB;
  half4 svA = *(const half4*)&hb[(size_t)n0*F + 4*fp];
  half4 svB = *(const half4*)&hb[(size_t)n1*F + 4*fp];
  float aA[4], aB[4];
  #pragma unroll
  for (int i = 0; i < 4; ++i){
    aA[i] = wsA*(float)svA[i];
    aB[i] = wsB*(float)svB[i];
  }
  int eA  = __builtin_amdgcn_readfirstlane(offs[n0]);
  int eM  = __builtin_amdgcn_readfirstlane(offs[n1]);
  int e1B = __builtin_amdgcn_readfirstlane(offs[n1+1]);
  int e1A = eM, eB = eM;
  // interleaved dual-chain batch-4 walk (R5 structure, half4 payload)
  while (eA + 4 <= e1A && eB + 4 <= e1B){
    int2 dA4[4], dB4[4];
    #pragma unroll
    for (int u = 0; u < 4; ++u) dA4[u] = edat[eA+u];
    #pragma unroll
    for (int u = 0; u < 4; ++u) dB4[u] = edat[eB+u];
    half4 vA[4], vB[4];
    #pragma unroll
    for (int u = 0; u < 4; ++u) vA[u] = *(const half4*)&hb[(size_t)dA4[u].x*F + 4*fp];
    #pragma unroll
    for (int u = 0; u < 4; ++u) vB[u] = *(const half4*)&hb[(size_t)dB4[u].x*F + 4*fp];
    #pragma unroll
    for (int u = 0; u < 4; ++u){
      float wA = __int_as_float(dA4[u].y), wB = __int_as_float(dB4[u].y);
      #pragma unroll
      for (int i = 0; i < 4; ++i){
        aA[i] = fmaf(wA, (float)vA[u][i], aA[i]);
        aB[i] = fmaf(wB, (float)vB[u][i], aB[i]);
      }
    }
    eA += 4; eB += 4;
  }
  // drain A
  for (; eA + 4 <= e1A; eA += 4){
    int2 d4[4];
    #pragma unroll
    for (int u = 0; u < 4; ++u) d4[u] = edat[eA+u];
    half4 vv[4];
    #pragma unroll
    for (int u = 0; u < 4; ++u) vv[u] = *(const half4*)&hb[(size_t)d4[u].x*F + 4*fp];
    #pragma unroll
    for (int u = 0; u < 4; ++u){
      float wu = __int_as_float(d4[u].y);
      #pragma unroll
      for (int i = 0; i < 4; ++i) aA[i] = fmaf(wu, (float)vv[u][i], aA[i]);
    }
  }
  for (; eA < e1A; ++eA){
    int2 du = edat[eA];
    float wu = __int_as_float(du.y);
    half4 vu = *(const half4*)&hb[(size_t)du.x*F + 4*fp];
    #pragma unroll
    for (int i = 0; i < 4; ++i) aA[i] = fmaf(wu, (float)vu[i], aA[i]);
  }
  // drain B
  for (; eB + 4 <= e1B; eB += 4){
    int2 d4[4];
    #pragma unroll
    for (int u = 0; u < 4; ++u) d4[u] = edat[eB+u];
    half4 vv[4];
    #pragma unroll
    for (int u = 0; u < 4; ++u) vv[u] = *(const half4*)&hb[(size_t)d4[u].x*F + 4*fp];
    #pragma unroll
    for (int u = 0; u < 4; ++u){
      float wu = __int_as_float(d4[u].y);
      #pragma unroll
      for (int i = 0; i < 4; ++i) aB[i] = fmaf(wu, (float)vv[u][i], aB[i]);
    }
  }
  for (; eB < e1B; ++eB){
    int2 du = edat[eB];
    float wu = __int_as_float(du.y);
    half4 vu = *(const half4*)&hb[(size_t)du.x*F + 4*fp];
    #pragma unroll
    for (int i = 0; i < 4; ++i) aB[i] = fmaf(wu, (float)vu[i], aB[i]);
  }
  half4 oA, oB;
  #pragma unroll
  for (int i = 0; i < 4; ++i){
    oA[i] = (_Float16)aA[i];
    oB[i] = (_Float16)aB[i];
  }
  *(half4*)&hout[((size_t)t*kNN + n0)*F + 4*fp] = oA;
  *(half4*)&hout[((size_t)t*kNN + n1)*F + 4*fp] = oB;
}

// MFMA GEMM: out[M,64] = relu(in[M,K] @ W[K,64] + bias). R11-verified
// (-15us vs scalar). Weights hi/lo-split fp16 -> fp32-exact product w.r.t.
// the already-fp16 activations. A-frag: row=lane&15, k=(lane>>4)*8+j.
// B-frag: W[k][n] direct. D: row=(lane>>4)*4+r, col=lane&15. Bias in C-init.
template<int K>
__global__ __launch_bounds__(256) void k_gemm_mfma(const _Float16* __restrict__ in,
                      const float* __restrict__ Wg, const float* __restrict__ bias,
                      _Float16* __restrict__ out){
  constexpr int N  = kHH;            // 64
  constexpr int KH = K/32;           // K-halves per MFMA chain
  constexpr int M  = kNN*kTT;        // 120000
  int tid = threadIdx.x, w = tid >> 6, lane = tid & 63;
  int lo = lane & 15, hi4 = lane >> 4;
  half8 BH_[4][KH], BL_[4][KH];
  #pragma unroll
  for (int nt = 0; nt < 4; ++nt){
    #pragma unroll
    for (int kh = 0; kh < KH; ++kh){
      half8 fh, fl;
      #pragma unroll
      for (int j = 0; j < 8; ++j){
        float wv = Wg[(size_t)(kh*32 + hi4*8 + j)*N + nt*16 + lo];
        _Float16 h = (_Float16)wv;
        fh[j] = h;
        fl[j] = (_Float16)(wv - (float)h);
      }
      BH_[nt][kh] = fh; BL_[nt][kh] = fl;
    }
  }
  float bb[4];
  #pragma unroll
  for (int nt = 0; nt < 4; ++nt) bb[nt] = bias[nt*16 + lo];
  int wbase = blockIdx.x*128 + w*32;
  half8 AF[2][KH];
  #pragma unroll
  for (int s = 0; s < 2; ++s){
    int mr = min(wbase + s*16 + lo, M-1);   // clamped tail
    #pragma unroll
    for (int kh = 0; kh < KH; ++kh)
      AF[s][kh] = *(const half8*)&in[(size_t)mr*K + kh*32 + hi4*8];
  }
  #pragma unroll
  for (int s = 0; s < 2; ++s){
    #pragma unroll
    for (int nt = 0; nt < 4; ++nt){
      floatx4 a = {bb[nt], bb[nt], bb[nt], bb[nt]};
      #pragma unroll
      for (int kh = 0; kh < KH; ++kh)
        a = __builtin_amdgcn_mfma_f32_16x16x32_f16(AF[s][kh], BL_[nt][kh], a, 0,0,0);
      #pragma unroll
      for (int kh = 0; kh < KH; ++kh)
        a = __builtin_amdgcn_mfma_f32_16x16x32_f16(AF[s][kh], BH_[nt][kh], a, 0,0,0);
      #pragma unroll
      for (int r = 0; r < 4; ++r){
        int m = wbase + s*16 + hi4*4 + r;
        if (m < M)
          out[(size_t)m*N + nt*16 + lo] = (_Float16)fmaxf(a[r], 0.f);
      }
    }
  }
}

// Fused 2-layer LSTM + FC, THREE 16-node tiles per block (48 nodes).
// R5-exact config: launch_bounds(512,2) / kNU=3 / 209 blocks, one dispatch
// round, VGPR=100, no spill. The 2-blocks/CU axis is CLOSED: twice (R1, R6)
// forcing a 128-reg budget spilled ~60MB of scratch.
// x input is T-MAJOR ((t*kNN+n)*64): all 209 blocks read the SAME 1.28MB
// t-slab each iteration (L2/L3-resident machine-wide).
constexpr int kNU = 3;                         // tiles per block
__global__ __launch_bounds__(512, 2) void k_rec2(const _Float16* __restrict__ xin,
                     const float* __restrict__ wih0, const float* __restrict__ whh0,
                     const float* __restrict__ bih0, const float* __restrict__ bhh0,
                     const float* __restrict__ wih1, const float* __restrict__ whh1,
                     const float* __restrict__ bih1, const float* __restrict__ bhh1,
                     const float* __restrict__ fcw, const float* __restrict__ fcb,
                     float* __restrict__ out){
  constexpr int LP = 72;                       // LDS row pitch (halves)
  constexpr size_t TS = (size_t)kNN*kHH;       // t-slab stride (elements)
  __shared__ _Float16 h0b[kNU][2][16*LP];      // [tile][dbuf]
  __shared__ _Float16 h1b[kNU][2][16*LP];
  int tid = threadIdx.x, w = tid >> 6, lane = tid & 63;
  int lo = lane & 15, hi4 = lane >> 4;
  int layer = w >> 2, wl = w & 3;
  int nb0 = blockIdx.x*(16*kNU);

  const float* wih = layer ? wih1 : wih0;
  const float* whh = layer ? whh1 : whh0;
  const float* bi_ = layer ? bih1 : bih0;
  const float* bh_ = layer ? bhh1 : bhh0;

  half8 BI[4][2], BH[4][2];
  #pragma unroll
  for (int q = 0; q < 4; ++q){
    int row = q*kHH + wl*16 + lo;
    #pragma unroll
    for (int kt = 0; kt < 2; ++kt){
      const float* pi = wih + (size_t)row*kHH + kt*32 + hi4*8;
      const float* ph = whh + (size_t)row*kHH + kt*32 + hi4*8;
      half8 fi, fh;
      #pragma unroll
      for (int j = 0; j < 8; ++j){ fi[j] = (_Float16)pi[j]; fh[j] = (_Float16)ph[j]; }
      BI[q][kt] = fi; BH[q][kt] = fh;
    }
  }
  float bias[4];
  #pragma unroll
  for (int q = 0; q < 4; ++q){
    int col = q*kHH + wl*16 + lo;
    bias[q] = bi_[col] + bh_[col];
  }

  float c[kNU][4];
  #pragma unroll
  for (int u = 0; u < kNU; ++u){c[u][0]=0.f;c[u][1]=0.f;c[u][2]=0.f;c[u][3]=0.f;}
  half8 ax[kNU][2], axn[kNU][2];

  size_t nrow[kNU];                  // node-row offset within a t-slab
  #pragma unroll
  for (int u = 0; u < kNU; ++u)
    nrow[u] = (size_t)min(nb0 + u*16 + lo, kNN-1)*kHH;
  if (layer == 0){
    #pragma unroll
    for (int u = 0; u < kNU; ++u)
      #pragma unroll
      for (int kt = 0; kt < 2; ++kt)
        axn[u][kt] = *(const half8*)&xin[nrow[u] + kt*32 + hi4*8];
  }

  for (int i = 0; i < 13; ++i){
    int t = layer ? i-1 : i;
    bool act = layer ? (i >= 1) : (i < 12);
    if (act){
      if (layer == 0){
        // consume prefetched x, then immediately issue next-t loads — a full
        // step of latency budget before use AND before the barrier drain.
        #pragma unroll
        for (int u = 0; u < kNU; ++u){
          ax[u][0] = axn[u][0]; ax[u][1] = axn[u][1];
        }
        if (t < kTT-1){
          const _Float16* xs = xin + (size_t)(t+1)*TS;
          #pragma unroll
          for (int u = 0; u < kNU; ++u)
            #pragma unroll
            for (int kt = 0; kt < 2; ++kt)
              axn[u][kt] = *(const half8*)&xs[nrow[u] + kt*32 + hi4*8];
        }
      }
      #pragma unroll
      for (int u = 0; u < kNU; ++u){
        // layer1 input = h0(t), written by layer0 in iter i-1 (buf t&1);
        // layer0 this iter writes buf (t+1)&1 -> no race.
        if (layer){
          const _Float16* rb = &h0b[u][t & 1][0];
          #pragma unroll
          for (int kt = 0; kt < 2; ++kt)
            ax[u][kt] = *(const half8*)&rb[lo*LP + kt*32 + hi4*8];
        }
        half8 ah[2];
        if (t > 0){
          // recurrent h(t-1): buf (t-1)&1, written iter i-1; this iter writes
          // buf t&1 -> no race.
          const _Float16* rb = layer ? &h1b[u][(t-1) & 1][0] : &h0b[u][(t-1) & 1][0];
          #pragma unroll
          for (int kt = 0; kt < 2; ++kt)
            ah[kt] = *(const half8*)&rb[lo*LP + kt*32 + hi4*8];
        }
        floatx4 acc[4];
        #pragma unroll
        for (int q = 0; q < 4; ++q){
          floatx4 a = {bias[q], bias[q], bias[q], bias[q]};
          a = __builtin_amdgcn_mfma_f32_16x16x32_f16(ax[u][0], BI[q][0], a, 0,0,0);
          a = __builtin_amdgcn_mfma_f32_16x16x32_f16(ax[u][1], BI[q][1], a, 0,0,0);
          acc[q] = a;
        }
        if (t > 0){
          #pragma unroll
          for (int q = 0; q < 4; ++q){
            floatx4 a = acc[q];
            a = __builtin_amdgcn_mfma_f32_16x16x32_f16(ah[0], BH[q][0], a, 0,0,0);
            a = __builtin_amdgcn_mfma_f32_16x16x32_f16(ah[1], BH[q][1], a, 0,0,0);
            acc[q] = a;
          }
        }
        _Float16* hb = layer ? &h1b[u][t & 1][0] : &h0b[u][t & 1][0];
        #pragma unroll
        for (int r = 0; r < 4; ++r){
          float ii = sigf(acc[0][r]);
          float ff = sigf(acc[1][r]);
          float gt = tanh_fast(acc[2][r]);
          float oo = sigf(acc[3][r]);
          c[u][r] = ff*c[u][r] + ii*gt;
          float hn = oo * tanh_fast(c[u][r]);
          hb[(hi4*4 + r)*LP + wl*16 + lo] = (_Float16)hn;
        }
      }
    }
    __syncthreads();
  }
  // FC: h1(t=11) sits in h1b[u][1]; waves 4..4+kNU-1 handle tiles 0..kNU-1.
  if (w >= 4 && w < 4 + kNU){
    int u = w - 4;
    const _Float16* rb = &h1b[u][1][0];
    half8 a0 = *(const half8*)&rb[lo*LP + 0*32 + hi4*8];
    half8 a1 = *(const half8*)&rb[lo*LP + 1*32 + hi4*8];
    half8 F0, F1;
    const float* pf = fcw + (size_t)lo*kHH + hi4*8;
    #pragma unroll
    for (int j = 0; j < 8; ++j){ F0[j] = (_Float16)pf[j]; F1[j] = (_Float16)pf[32+j]; }
    floatx4 a = {0.f,0.f,0.f,0.f};
    a = __builtin_amdgcn_mfma_f32_16x16x32_f16(a0, F0, a, 0,0,0);
    a = __builtin_amdgcn_mfma_f32_16x16x32_f16(a1, F1, a, 0,0,0);
    float bo = fcb[lo];
    #pragma unroll
    for (int r = 0; r < 4; ++r){
      int n = nb0 + u*16 + hi4*4 + r;
      if (n < kNN) out[(size_t)n*kOUT + lo] = a[r] + bo;
    }
  }
}

extern "C" void kernel_launch(void* const* d_in, const int* in_sizes, int n_in,
                              void* d_out, int out_size, void* d_ws, size_t ws_size,
                              hipStream_t stream){
  const float* x    = (const float*)d_in[0];
  const int*   ei   = (const int*)  d_in[1];
  const float* gw0  = (const float*)d_in[2];
  const float* gb0  = (const float*)d_in[3];
  const float* gw1  = (const float*)d_in[4];
  const float* gb1  = (const float*)d_in[5];
  const float* wih0 = (const float*)d_in[6];
  const float* whh0 = (const float*)d_in[7];
  const float* bih0 = (const float*)d_in[8];
  const float* bhh0 = (const float*)d_in[9];
  const float* wih1 = (const float*)d_in[10];
  const float* whh1 = (const float*)d_in[11];
  const float* bih1 = (const float*)d_in[12];
  const float* bhh1 = (const float*)d_in[13];
  const float* fcw  = (const float*)d_in[14];
  const float* fcb  = (const float*)d_in[15];
  float* out = (float*)d_out;

  char* ws = (char*)d_ws;
  size_t p = 0;
  auto carve = [&](size_t bytes)->char*{
    char* r = ws + p;
    p += (bytes + 255) & ~(size_t)255;
    return r;
  };
  int*   cnt  = (int*)  carve(sizeof(int)*kNN);
  int*   cur  = (int*)  carve(sizeof(int)*kNN);
  int*   pb   = (int*)  carve(sizeof(int)*kDB);
  int*   offs = (int*)  carve(sizeof(int)*(kNN+1));
  float* dis  = (float*)carve(sizeof(float)*kNN);
  int2*  edat = (int2*) carve(sizeof(int2)*kNE);
  _Float16* aggX = (_Float16*)carve(sizeof(_Float16)*(size_t)kNN*kTT*kFIN); // 7.68MB
  _Float16* bufA = (_Float16*)carve(sizeof(_Float16)*(size_t)kNN*kTT*kHH);  // 15.36MB
  _Float16* bufB = (_Float16*)carve(sizeof(_Float16)*(size_t)kNN*kTT*kHH);  // 15.36MB
  (void)ws_size; (void)out_size;

  // is64 determined on HOST from in_sizes[1] byte count (R12; fallback to
  // device-side detection if ambiguous).
  int is64_host = -1;
  if (in_sizes != nullptr && n_in > 1){
    if      (in_sizes[1] == (int)(2u*kNE*8u)) is64_host = 1;
    else if (in_sizes[1] == (int)(2u*kNE*4u)) is64_host = 0;
  }
  if (is64_host < 0){
    k_detect_zero<<<kDB, 256, 0, stream>>>(ei, pb, cnt);   // also zeroes cnt
  } else {
    hipMemsetAsync(cnt, 0, sizeof(int)*kNN, stream);       // 40KB fill
  }
  k_deg    <<<(kNE+255)/256, 256, 0, stream>>>(ei, pb, cnt, is64_host);
  k_scan   <<<1, 1024, 0, stream>>>(cnt, offs, cur, dis);
  k_scatter<<<(kNE+255)/256, 256, 0, stream>>>(ei, pb, cur, dis, edat, is64_host);

  // GCN-0: aggregate 32-feat fp32 x (A_hat x), then MFMA GEMM (+gb0+relu)
  k_agg<kFIN, float><<<(kNN/2*(kTT/4) + 3)/4, 256, 0, stream>>>(x, aggX, dis, offs, edat);
  k_gemm_mfma<kFIN><<<(kNN*kTT + 127)/128, 256, 0, stream>>>(aggX, gw0, gb0, bufB);
  // GCN-1: aggregate 64-feat (half4, 3 edge-walk passes), MFMA GEMM (+gb1+relu)
  k_agg64<<<(kNN/2*(kTT/4)) / 4, 256, 0, stream>>>(bufB, bufA, dis, offs, edat);
  k_gemm_mfma<kHH><<<(kNN*kTT + 127)/128, 256, 0, stream>>>(bufA, gw1, gb1, bufB);

  // Fused 2-layer LSTM + FC -> out (three 16-node tiles per block, t-major x)
  k_rec2<<<(kNN + 16*kNU - 1)/(16*kNU), 512, 0, stream>>>(bufB, wih0, whh0, bih0, bhh0,
                                          wih1, whh1, bih1, bhh1, fcw, fcb, out);
}

// Round 14
// 235.625 us; speedup vs baseline: 1.0164x; 1.0164x over previous
//
#include <hip/hip_runtime.h>
#include <hip/hip_bf16.h>

constexpr int kNN  = 10000;   // nodes
constexpr int kTT  = 12;      // timesteps
constexpr int kFIN = 32;      // input features
constexpr int kHH  = 64;      // hidden
constexpr int kH4  = 256;     // 4*hidden (gates)
constexpr int kOUT = 16;      // output features
constexpr int kNE  = 160000;  // edges
constexpr int kDB  = 256;     // detect blocks (pb[] partials, fallback path)

typedef _Float16 half8 __attribute__((ext_vector_type(8)));
typedef _Float16 half4 __attribute__((ext_vector_type(4)));
typedef _Float16 half2t __attribute__((ext_vector_type(2)));
typedef float floatx4 __attribute__((ext_vector_type(4)));

// Minimal-instruction activations: raw exp2 form, NO clamp needed —
// exp2(+inf)->inf, rcp(inf)->0 and exp2(-inf)->0 saturate both functions to
// the correct +-1 / {0,1} limits. sig: 4 VALU; tanh: 5 VALU.
__device__ __forceinline__ float rcp_fast(float x){ return __builtin_amdgcn_rcpf(x); }
__device__ __forceinline__ float sigf(float x){
  return rcp_fast(1.f + __builtin_amdgcn_exp2f(-1.44269504f*x));
}
__device__ __forceinline__ float tanh_fast(float x){
  return fmaf(-2.f, rcp_fast(__builtin_amdgcn_exp2f(2.88539008f*x) + 1.f), 1.f);
}

// Typed 2-element gather load -> float2.
__device__ __forceinline__ float2 ld2f(const _Float16* p){
  half2t h = *(const half2t*)p; return make_float2((float)h[0], (float)h[1]);
}
__device__ __forceinline__ float2 ld2f(const float* p){
  return *(const float2*)p;
}

// FALLBACK int64-vs-int32 detection (odd words all zero <=> int64) + cnt
// zeroing. Only launched when in_sizes is ambiguous (normal path determines
// is64 on HOST from in_sizes[1] byte count).
__global__ void k_detect_zero(const int* __restrict__ ei, int* __restrict__ pb,
                              int* __restrict__ cnt){
  int a = 0;
  for (int i = blockIdx.x*256 + threadIdx.x; i < kNE; i += gridDim.x*256)
    a |= ei[2*i+1];
  unsigned long long m = __ballot(a != 0);
  __shared__ int bf;
  if (threadIdx.x == 0) bf = 0;
  __syncthreads();
  if (m && (threadIdx.x & 63) == 0) atomicOr(&bf, 1);
  __syncthreads();
  if (threadIdx.x == 0) pb[blockIdx.x] = bf;
  for (int i = blockIdx.x*256 + threadIdx.x; i < kNN; i += gridDim.x*256)
    cnt[i] = 0;
}

// Resolve is64: host-determined (is64h >= 0) or reduce pb[] (fallback).
__device__ __forceinline__ bool resolve_is64(int is64h, const int* __restrict__ pb,
                                             int* sflag){
  if (is64h >= 0) return is64h == 1;
  int v = 0;
  for (int i = threadIdx.x; i < kDB; i += 256) v |= pb[i];
  if (threadIdx.x == 0) *sflag = 0;
  __syncthreads();
  if (v) atomicOr(sflag, 1);
  __syncthreads();
  return (*sflag == 0);            // odd words all zero <=> int64 input
}

// Degree count + x fp32->fp16 cast (round-14). The cast is BACK — not for
// dispatch-count reasons but for L2 LINE-RATE: aggs are bound by cache-line
// requests (160K edges x 12t x lines/row); fp32 x rows are 128B = 2 lines,
// fp16 rows are 64B = 1 line -> agg32's line traffic HALVES, and its per-pass
// slab working set drops 5.1->2.56MB (fits each XCD's 4MB L2). Fused here
// (this 625-block dispatch has idle capacity) -> zero extra dispatches.
__global__ void k_deg(const int* __restrict__ ei, const int* __restrict__ pb,
                      int* __restrict__ cnt, int is64h,
                      const float* __restrict__ x, _Float16* __restrict__ xh){
  __shared__ int sflag;
  bool is64 = resolve_is64(is64h, pb, &sflag);
  int e = blockIdx.x*256 + threadIdx.x;
  if (e < kNE){
    int c = is64 ? ei[2*(kNE+e)] : ei[kNE+e];
    atomicAdd(&cnt[c], 1);
  }
  const int NV = kNN*kTT*kFIN/4;
  for (int i = blockIdx.x*256 + threadIdx.x; i < NV; i += gridDim.x*256){
    float4 v = *(const float4*)&x[4*i];
    half4 h;
    h[0]=(_Float16)v.x; h[1]=(_Float16)v.y; h[2]=(_Float16)v.z; h[3]=(_Float16)v.w;
    *(half4*)&xh[4*i] = h;
  }
}

// Exclusive scan of in-degree (single block, 1024 threads) + dis =
// rsqrt(deg+selfloop) + cur initialized to offs (scatter mutates cur only).
__global__ __launch_bounds__(1024) void k_scan(const int* __restrict__ cnt,
                       int* __restrict__ offs, int* __restrict__ cur,
                       float* __restrict__ dis){
  __shared__ int wsum[16];
  int tid = threadIdx.x;
  const int NT = 1024;
  const int CH = (kNN + NT - 1)/NT;
  int lo = tid*CH, hi = min(lo+CH, kNN);
  int s = 0;
  for (int i = lo; i < hi; ++i) s += cnt[i];
  int orig = s;
  int lane = tid & 63, wv = tid >> 6;
  #pragma unroll
  for (int d = 1; d < 64; d <<= 1){
    int v = __shfl_up(s, d, 64);
    if (lane >= d) s += v;
  }
  if (lane == 63) wsum[wv] = s;
  __syncthreads();
  int add = 0;
  for (int k2 = 0; k2 < wv; ++k2) add += wsum[k2];
  int run = s - orig + add;          // exclusive prefix for this thread's chunk
  for (int i = lo; i < hi; ++i){ offs[i] = run; cur[i] = run; run += cnt[i]; }
  if (hi == kNN) offs[kNN] = run;
  for (int i = tid; i < kNN; i += NT) dis[i] = rsqrtf((float)(cnt[i]+1));
}

// CSR scatter; packs (src, weight) into one int2 per edge. Slot comes
// straight from atomicAdd on cur (pre-initialized to offs by k_scan).
__global__ void k_scatter(const int* __restrict__ ei, const int* __restrict__ pb,
                          int* __restrict__ cur, const float* __restrict__ dis,
                          int2* __restrict__ edat, int is64h){
  __shared__ int sflag;
  bool is64 = resolve_is64(is64h, pb, &sflag);
  int e = blockIdx.x*256 + threadIdx.x;
  if (e >= kNE) return;
  int r = is64 ? ei[2*e]       : ei[e];
  int c = is64 ? ei[2*(kNE+e)] : ei[kNE+e];
  int p = atomicAdd(&cur[c], 1);
  edat[p] = make_int2(r, __float_as_int(dis[r]*dis[c]));
}

// GCN aggregation for F=32 (fp16 input rows: 64B = ONE cache line per
// edge-t gather) — R5-verified wave structure (t-slab L2-resident,
// dual-node interleaved batch-4 walk).
template<int F, typename TIN>
__global__ __launch_bounds__(256) void k_agg(const TIN* __restrict__ hin,
                     _Float16* __restrict__ hout,
                     const float* __restrict__ dis,
                     const int* __restrict__ offs, const int2* __restrict__ edat){
  constexpr int LPF = F/2;            // lanes per timestep
  constexpr int TPW = 64/LPF;         // timesteps per wave
  constexpr int NP  = kNN/2;          // node pairs
  int wid = threadIdx.x >> 6, lane = threadIdx.x & 63;
  int gw = blockIdx.x*4 + wid;        // gw = tq*NP + np
  int tq = gw / NP, np = gw - tq*NP;
  int n0 = 2*np, n1 = n0 + 1;
  int fp = lane & (LPF-1), tsub = lane / LPF;
  int t = TPW*tq + tsub;
  const TIN* hb = hin + (size_t)t*kNN*F;
  float dA = dis[n0], dB = dis[n1];
  float2 svA = ld2f(&hb[(size_t)n0*F + 2*fp]);
  float2 svB = ld2f(&hb[(size_t)n1*F + 2*fp]);
  float a0 = dA*dA*svA.x, a1 = dA*dA*svA.y;
  float b0 = dB*dB*svB.x, b1 = dB*dB*svB.y;
  int eA  = __builtin_amdgcn_readfirstlane(offs[n0]);
  int eM  = __builtin_amdgcn_readfirstlane(offs[n1]);
  int e1B = __builtin_amdgcn_readfirstlane(offs[n1+1]);
  int e1A = eM, eB = eM;
  while (eA + 4 <= e1A && eB + 4 <= e1B){
    int2 dA4[4], dB4[4];
    #pragma unroll
    for (int u = 0; u < 4; ++u) dA4[u] = edat[eA+u];
    #pragma unroll
    for (int u = 0; u < 4; ++u) dB4[u] = edat[eB+u];
    float2 vA[4], vB[4];
    #pragma unroll
    for (int u = 0; u < 4; ++u) vA[u] = ld2f(&hb[(size_t)dA4[u].x*F + 2*fp]);
    #pragma unroll
    for (int u = 0; u < 4; ++u) vB[u] = ld2f(&hb[(size_t)dB4[u].x*F + 2*fp]);
    #pragma unroll
    for (int u = 0; u < 4; ++u){
      float wA = __int_as_float(dA4[u].y), wB = __int_as_float(dB4[u].y);
      a0 = fmaf(wA, vA[u].x, a0);
      a1 = fmaf(wA, vA[u].y, a1);
      b0 = fmaf(wB, vB[u].x, b0);
      b1 = fmaf(wB, vB[u].y, b1);
    }
    eA += 4; eB += 4;
  }
  // drain A
  for (; eA + 4 <= e1A; eA += 4){
    int2 d4[4];
    #pragma unroll
    for (int u = 0; u < 4; ++u) d4[u] = edat[eA+u];
    float2 vv[4];
    #pragma unroll
    for (int u = 0; u < 4; ++u) vv[u] = ld2f(&hb[(size_t)d4[u].x*F + 2*fp]);
    #pragma unroll
    for (int u = 0; u < 4; ++u){
      float wu = __int_as_float(d4[u].y);
      a0 = fmaf(wu, vv[u].x, a0);
      a1 = fmaf(wu, vv[u].y, a1);
    }
  }
  for (; eA < e1A; ++eA){
    int2 du = edat[eA];
    float wu = __int_as_float(du.y);
    float2 vu = ld2f(&hb[(size_t)du.x*F + 2*fp]);
    a0 = fmaf(wu, vu.x, a0);
    a1 = fmaf(wu, vu.y, a1);
  }
  // drain B
  for (; eB + 4 <= e1B; eB += 4){
    int2 d4[4];
    #pragma unroll
    for (int u = 0; u < 4; ++u) d4[u] = edat[eB+u];
    float2 vv[4];
    #pragma unroll
    for (int u = 0; u < 4; ++u) vv[u] = ld2f(&hb[(size_t)d4[u].x*F + 2*fp]);
    #pragma unroll
    for (int u = 0; u < 4; ++u){
      float wu = __int_as_float(d4[u].y);
      b0 = fmaf(wu, vv[u].x, b0);
      b1 = fmaf(wu, vv[u].y, b1);
    }
  }
  for (; eB < e1B; ++eB){
    int2 du = edat[eB];
    float wu = __int_as_float(du.y);
    float2 vu = ld2f(&hb[(size_t)du.x*F + 2*fp]);
    b0 = fmaf(wu, vu.x, b0);
    b1 = fmaf(wu, vu.y, b1);
  }
  half2t oA; oA[0] = (_Float16)a0; oA[1] = (_Float16)a1;
  *(half2t*)&hout[((size_t)t*kNN + n0)*F + 2*fp] = oA;
  half2t oB; oB[0] = (_Float16)b0; oB[1] = (_Float16)b1;
  *(half2t*)&hout[((size_t)t*kNN + n1)*F + 2*fp] = oB;
}

// GCN aggregation for F=64 — half4 gathers (R13, neutral but fewer instrs):
// 16 lanes cover a 64-feat row, wave spans 4 timesteps, 3 edge-walk passes.
__global__ __launch_bounds__(256) void k_agg64(const _Float16* __restrict__ hin,
                     _Float16* __restrict__ hout,
                     const float* __restrict__ dis,
                     const int* __restrict__ offs, const int2* __restrict__ edat){
  constexpr int F   = kHH;            // 64
  constexpr int NP  = kNN/2;          // node pairs
  int wid = threadIdx.x >> 6, lane = threadIdx.x & 63;
  int gw = blockIdx.x*4 + wid;        // gw = tq*NP + np, tq in [0,3)
  int tq = gw / NP, np = gw - tq*NP;
  int n0 = 2*np, n1 = n0 + 1;
  int fp = lane & 15, tsub = lane >> 4;
  int t = tq*4 + tsub;                // 4 t-slices per wave
  const _Float16* hb = hin + (size_t)t*kNN*F;
  float dA = dis[n0], dB = dis[n1];
  float wsA = dA*dA, wsB = dB*dB;
  half4 svA = *(const half4*)&hb[(size_t)n0*F + 4*fp];
  half4 svB = *(const half4*)&hb[(size_t)n1*F + 4*fp];
  float aA[4], aB[4];
  #pragma unroll
  for (int i = 0; i < 4; ++i){
    aA[i] = wsA*(float)svA[i];
    aB[i] = wsB*(float)svB[i];
  }
  int eA  = __builtin_amdgcn_readfirstlane(offs[n0]);
  int eM  = __builtin_amdgcn_readfirstlane(offs[n1]);
  int e1B = __builtin_amdgcn_readfirstlane(offs[n1+1]);
  int e1A = eM, eB = eM;
  while (eA + 4 <= e1A && eB + 4 <= e1B){
    int2 dA4[4], dB4[4];
    #pragma unroll
    for (int u = 0; u < 4; ++u) dA4[u] = edat[eA+u];
    #pragma unroll
    for (int u = 0; u < 4; ++u) dB4[u] = edat[eB+u];
    half4 vA[4], vB[4];
    #pragma unroll
    for (int u = 0; u < 4; ++u) vA[u] = *(const half4*)&hb[(size_t)dA4[u].x*F + 4*fp];
    #pragma unroll
    for (int u = 0; u < 4; ++u) vB[u] = *(const half4*)&hb[(size_t)dB4[u].x*F + 4*fp];
    #pragma unroll
    for (int u = 0; u < 4; ++u){
      float wA = __int_as_float(dA4[u].y), wB = __int_as_float(dB4[u].y);
      #pragma unroll
      for (int i = 0; i < 4; ++i){
        aA[i] = fmaf(wA, (float)vA[u][i], aA[i]);
        aB[i] = fmaf(wB, (float)vB[u][i], aB[i]);
      }
    }
    eA += 4; eB += 4;
  }
  // drain A
  for (; eA + 4 <= e1A; eA += 4){
    int2 d4[4];
    #pragma unroll
    for (int u = 0; u < 4; ++u) d4[u] = edat[eA+u];
    half4 vv[4];
    #pragma unroll
    for (int u = 0; u < 4; ++u) vv[u] = *(const half4*)&hb[(size_t)d4[u].x*F + 4*fp];
    #pragma unroll
    for (int u = 0; u < 4; ++u){
      float wu = __int_as_float(d4[u].y);
      #pragma unroll
      for (int i = 0; i < 4; ++i) aA[i] = fmaf(wu, (float)vv[u][i], aA[i]);
    }
  }
  for (; eA < e1A; ++eA){
    int2 du = edat[eA];
    float wu = __int_as_float(du.y);
    half4 vu = *(const half4*)&hb[(size_t)du.x*F + 4*fp];
    #pragma unroll
    for (int i = 0; i < 4; ++i) aA[i] = fmaf(wu, (float)vu[i], aA[i]);
  }
  // drain B
  for (; eB + 4 <= e1B; eB += 4){
    int2 d4[4];
    #pragma unroll
    for (int u = 0; u < 4; ++u) d4[u] = edat[eB+u];
    half4 vv[4];
    #pragma unroll
    for (int u = 0; u < 4; ++u) vv[u] = *(const half4*)&hb[(size_t)d4[u].x*F + 4*fp];
    #pragma unroll
    for (int u = 0; u < 4; ++u){
      float wu = __int_as_float(d4[u].y);
      #pragma unroll
      for (int i = 0; i < 4; ++i) aB[i] = fmaf(wu, (float)vv[u][i], aB[i]);
    }
  }
  for (; eB < e1B; ++eB){
    int2 du = edat[eB];
    float wu = __int_as_float(du.y);
    half4 vu = *(const half4*)&hb[(size_t)du.x*F + 4*fp];
    #pragma unroll
    for (int i = 0; i < 4; ++i) aB[i] = fmaf(wu, (float)vu[i], aB[i]);
  }
  half4 oA, oB;
  #pragma unroll
  for (int i = 0; i < 4; ++i){
    oA[i] = (_Float16)aA[i];
    oB[i] = (_Float16)aB[i];
  }
  *(half4*)&hout[((size_t)t*kNN + n0)*F + 4*fp] = oA;
  *(half4*)&hout[((size_t)t*kNN + n1)*F + 4*fp] = oB;
}

// MFMA GEMM: out[M,64] = relu(in[M,K] @ W[K,64] + bias). R11-verified
// (-15us vs scalar). Weights hi/lo-split fp16 -> fp32-exact product w.r.t.
// the already-fp16 activations. A-frag: row=lane&15, k=(lane>>4)*8+j.
// B-frag: W[k][n] direct. D: row=(lane>>4)*4+r, col=lane&15. Bias in C-init.
template<int K>
__global__ __launch_bounds__(256) void k_gemm_mfma(const _Float16* __restrict__ in,
                      const float* __restrict__ Wg, const float* __restrict__ bias,
                      _Float16* __restrict__ out){
  constexpr int N  = kHH;            // 64
  constexpr int KH = K/32;           // K-halves per MFMA chain
  constexpr int M  = kNN*kTT;        // 120000
  int tid = threadIdx.x, w = tid >> 6, lane = tid & 63;
  int lo = lane & 15, hi4 = lane >> 4;
  half8 BH_[4][KH], BL_[4][KH];
  #pragma unroll
  for (int nt = 0; nt < 4; ++nt){
    #pragma unroll
    for (int kh = 0; kh < KH; ++kh){
      half8 fh, fl;
      #pragma unroll
      for (int j = 0; j < 8; ++j){
        float wv = Wg[(size_t)(kh*32 + hi4*8 + j)*N + nt*16 + lo];
        _Float16 h = (_Float16)wv;
        fh[j] = h;
        fl[j] = (_Float16)(wv - (float)h);
      }
      BH_[nt][kh] = fh; BL_[nt][kh] = fl;
    }
  }
  float bb[4];
  #pragma unroll
  for (int nt = 0; nt < 4; ++nt) bb[nt] = bias[nt*16 + lo];
  int wbase = blockIdx.x*128 + w*32;
  half8 AF[2][KH];
  #pragma unroll
  for (int s = 0; s < 2; ++s){
    int mr = min(wbase + s*16 + lo, M-1);   // clamped tail
    #pragma unroll
    for (int kh = 0; kh < KH; ++kh)
      AF[s][kh] = *(const half8*)&in[(size_t)mr*K + kh*32 + hi4*8];
  }
  #pragma unroll
  for (int s = 0; s < 2; ++s){
    #pragma unroll
    for (int nt = 0; nt < 4; ++nt){
      floatx4 a = {bb[nt], bb[nt], bb[nt], bb[nt]};
      #pragma unroll
      for (int kh = 0; kh < KH; ++kh)
        a = __builtin_amdgcn_mfma_f32_16x16x32_f16(AF[s][kh], BL_[nt][kh], a, 0,0,0);
      #pragma unroll
      for (int kh = 0; kh < KH; ++kh)
        a = __builtin_amdgcn_mfma_f32_16x16x32_f16(AF[s][kh], BH_[nt][kh], a, 0,0,0);
      #pragma unroll
      for (int r = 0; r < 4; ++r){
        int m = wbase + s*16 + hi4*4 + r;
        if (m < M)
          out[(size_t)m*N + nt*16 + lo] = (_Float16)fmaxf(a[r], 0.f);
      }
    }
  }
}

// Fused 2-layer LSTM + FC, THREE 16-node tiles per block (48 nodes).
// R5-exact config: launch_bounds(512,2) / kNU=3 / 209 blocks, one dispatch
// round, VGPR=100, no spill. The 2-blocks/CU axis is CLOSED: twice (R1, R6)
// forcing a 128-reg budget spilled ~60MB of scratch.
// x input is T-MAJOR ((t*kNN+n)*64): all 209 blocks read the SAME 1.28MB
// t-slab each iteration (L2/L3-resident machine-wide).
constexpr int kNU = 3;                         // tiles per block
__global__ __launch_bounds__(512, 2) void k_rec2(const _Float16* __restrict__ xin,
                     const float* __restrict__ wih0, const float* __restrict__ whh0,
                     const float* __restrict__ bih0, const float* __restrict__ bhh0,
                     const float* __restrict__ wih1, const float* __restrict__ whh1,
                     const float* __restrict__ bih1, const float* __restrict__ bhh1,
                     const float* __restrict__ fcw, const float* __restrict__ fcb,
                     float* __restrict__ out){
  constexpr int LP = 72;                       // LDS row pitch (halves)
  constexpr size_t TS = (size_t)kNN*kHH;       // t-slab stride (elements)
  __shared__ _Float16 h0b[kNU][2][16*LP];      // [tile][dbuf]
  __shared__ _Float16 h1b[kNU][2][16*LP];
  int tid = threadIdx.x, w = tid >> 6, lane = tid & 63;
  int lo = lane & 15, hi4 = lane >> 4;
  int layer = w >> 2, wl = w & 3;
  int nb0 = blockIdx.x*(16*kNU);

  const float* wih = layer ? wih1 : wih0;
  const float* whh = layer ? whh1 : whh0;
  const float* bi_ = layer ? bih1 : bih0;
  const float* bh_ = layer ? bhh1 : bhh0;

  half8 BI[4][2], BH[4][2];
  #pragma unroll
  for (int q = 0; q < 4; ++q){
    int row = q*kHH + wl*16 + lo;
    #pragma unroll
    for (int kt = 0; kt < 2; ++kt){
      const float* pi = wih + (size_t)row*kHH + kt*32 + hi4*8;
      const float* ph = whh + (size_t)row*kHH + kt*32 + hi4*8;
      half8 fi, fh;
      #pragma unroll
      for (int j = 0; j < 8; ++j){ fi[j] = (_Float16)pi[j]; fh[j] = (_Float16)ph[j]; }
      BI[q][kt] = fi; BH[q][kt] = fh;
    }
  }
  float bias[4];
  #pragma unroll
  for (int q = 0; q < 4; ++q){
    int col = q*kHH + wl*16 + lo;
    bias[q] = bi_[col] + bh_[col];
  }

  float c[kNU][4];
  #pragma unroll
  for (int u = 0; u < kNU; ++u){c[u][0]=0.f;c[u][1]=0.f;c[u][2]=0.f;c[u][3]=0.f;}
  half8 ax[kNU][2], axn[kNU][2];

  size_t nrow[kNU];                  // node-row offset within a t-slab
  #pragma unroll
  for (int u = 0; u < kNU; ++u)
    nrow[u] = (size_t)min(nb0 + u*16 + lo, kNN-1)*kHH;
  if (layer == 0){
    #pragma unroll
    for (int u = 0; u < kNU; ++u)
      #pragma unroll
      for (int kt = 0; kt < 2; ++kt)
        axn[u][kt] = *(const half8*)&xin[nrow[u] + kt*32 + hi4*8];
  }

  for (int i = 0; i < 13; ++i){
    int t = layer ? i-1 : i;
    bool act = layer ? (i >= 1) : (i < 12);
    if (act){
      if (layer == 0){
        // consume prefetched x, then immediately issue next-t loads — a full
        // step of latency budget before use AND before the barrier drain.
        #pragma unroll
        for (int u = 0; u < kNU; ++u){
          ax[u][0] = axn[u][0]; ax[u][1] = axn[u][1];
        }
        if (t < kTT-1){
          const _Float16* xs = xin + (size_t)(t+1)*TS;
          #pragma unroll
          for (int u = 0; u < kNU; ++u)
            #pragma unroll
            for (int kt = 0; kt < 2; ++kt)
              axn[u][kt] = *(const half8*)&xs[nrow[u] + kt*32 + hi4*8];
        }
      }
      #pragma unroll
      for (int u = 0; u < kNU; ++u){
        // layer1 input = h0(t), written by layer0 in iter i-1 (buf t&1);
        // layer0 this iter writes buf (t+1)&1 -> no race.
        if (layer){
          const _Float16* rb = &h0b[u][t & 1][0];
          #pragma unroll
          for (int kt = 0; kt < 2; ++kt)
            ax[u][kt] = *(const half8*)&rb[lo*LP + kt*32 + hi4*8];
        }
        half8 ah[2];
        if (t > 0){
          // recurrent h(t-1): buf (t-1)&1, written iter i-1; this iter writes
          // buf t&1 -> no race.
          const _Float16* rb = layer ? &h1b[u][(t-1) & 1][0] : &h0b[u][(t-1) & 1][0];
          #pragma unroll
          for (int kt = 0; kt < 2; ++kt)
            ah[kt] = *(const half8*)&rb[lo*LP + kt*32 + hi4*8];
        }
        floatx4 acc[4];
        #pragma unroll
        for (int q = 0; q < 4; ++q){
          floatx4 a = {bias[q], bias[q], bias[q], bias[q]};
          a = __builtin_amdgcn_mfma_f32_16x16x32_f16(ax[u][0], BI[q][0], a, 0,0,0);
          a = __builtin_amdgcn_mfma_f32_16x16x32_f16(ax[u][1], BI[q][1], a, 0,0,0);
          acc[q] = a;
        }
        if (t > 0){
          #pragma unroll
          for (int q = 0; q < 4; ++q){
            floatx4 a = acc[q];
            a = __builtin_amdgcn_mfma_f32_16x16x32_f16(ah[0], BH[q][0], a, 0,0,0);
            a = __builtin_amdgcn_mfma_f32_16x16x32_f16(ah[1], BH[q][1], a, 0,0,0);
            acc[q] = a;
          }
        }
        _Float16* hb = layer ? &h1b[u][t & 1][0] : &h0b[u][t & 1][0];
        #pragma unroll
        for (int r = 0; r < 4; ++r){
          float ii = sigf(acc[0][r]);
          float ff = sigf(acc[1][r]);
          float gt = tanh_fast(acc[2][r]);
          float oo = sigf(acc[3][r]);
          c[u][r] = ff*c[u][r] + ii*gt;
          float hn = oo * tanh_fast(c[u][r]);
          hb[(hi4*4 + r)*LP + wl*16 + lo] = (_Float16)hn;
        }
      }
    }
    __syncthreads();
  }
  // FC: h1(t=11) sits in h1b[u][1]; waves 4..4+kNU-1 handle tiles 0..kNU-1.
  if (w >= 4 && w < 4 + kNU){
    int u = w - 4;
    const _Float16* rb = &h1b[u][1][0];
    half8 a0 = *(const half8*)&rb[lo*LP + 0*32 + hi4*8];
    half8 a1 = *(const half8*)&rb[lo*LP + 1*32 + hi4*8];
    half8 F0, F1;
    const float* pf = fcw + (size_t)lo*kHH + hi4*8;
    #pragma unroll
    for (int j = 0; j < 8; ++j){ F0[j] = (_Float16)pf[j]; F1[j] = (_Float16)pf[32+j]; }
    floatx4 a = {0.f,0.f,0.f,0.f};
    a = __builtin_amdgcn_mfma_f32_16x16x32_f16(a0, F0, a, 0,0,0);
    a = __builtin_amdgcn_mfma_f32_16x16x32_f16(a1, F1, a, 0,0,0);
    float bo = fcb[lo];
    #pragma unroll
    for (int r = 0; r < 4; ++r){
      int n = nb0 + u*16 + hi4*4 + r;
      if (n < kNN) out[(size_t)n*kOUT + lo] = a[r] + bo;
    }
  }
}

extern "C" void kernel_launch(void* const* d_in, const int* in_sizes, int n_in,
                              void* d_out, int out_size, void* d_ws, size_t ws_size,
                              hipStream_t stream){
  const float* x    = (const float*)d_in[0];
  const int*   ei   = (const int*)  d_in[1];
  const float* gw0  = (const float*)d_in[2];
  const float* gb0  = (const float*)d_in[3];
  const float* gw1  = (const float*)d_in[4];
  const float* gb1  = (const float*)d_in[5];
  const float* wih0 = (const float*)d_in[6];
  const float* whh0 = (const float*)d_in[7];
  const float* bih0 = (const float*)d_in[8];
  const float* bhh0 = (const float*)d_in[9];
  const float* wih1 = (const float*)d_in[10];
  const float* whh1 = (const float*)d_in[11];
  const float* bih1 = (const float*)d_in[12];
  const float* bhh1 = (const float*)d_in[13];
  const float* fcw  = (const float*)d_in[14];
  const float* fcb  = (const float*)d_in[15];
  float* out = (float*)d_out;

  char* ws = (char*)d_ws;
  size_t p = 0;
  auto carve = [&](size_t bytes)->char*{
    char* r = ws + p;
    p += (bytes + 255) & ~(size_t)255;
    return r;
  };
  int*   cnt  = (int*)  carve(sizeof(int)*kNN);
  int*   cur  = (int*)  carve(sizeof(int)*kNN);
  int*   pb   = (int*)  carve(sizeof(int)*kDB);
  int*   offs = (int*)  carve(sizeof(int)*(kNN+1));
  float* dis  = (float*)carve(sizeof(float)*kNN);
  int2*  edat = (int2*) carve(sizeof(int2)*kNE);
  _Float16* xh   = (_Float16*)carve(sizeof(_Float16)*(size_t)kNN*kTT*kFIN); // 7.68MB
  _Float16* aggX = (_Float16*)carve(sizeof(_Float16)*(size_t)kNN*kTT*kFIN); // 7.68MB
  _Float16* bufA = (_Float16*)carve(sizeof(_Float16)*(size_t)kNN*kTT*kHH);  // 15.36MB
  _Float16* bufB = (_Float16*)carve(sizeof(_Float16)*(size_t)kNN*kTT*kHH);  // 15.36MB
  (void)ws_size; (void)out_size;

  // is64 determined on HOST from in_sizes[1] byte count (R12; fallback to
  // device-side detection if ambiguous).
  int is64_host = -1;
  if (in_sizes != nullptr && n_in > 1){
    if      (in_sizes[1] == (int)(2u*kNE*8u)) is64_host = 1;
    else if (in_sizes[1] == (int)(2u*kNE*4u)) is64_host = 0;
  }
  if (is64_host < 0){
    k_detect_zero<<<kDB, 256, 0, stream>>>(ei, pb, cnt);   // also zeroes cnt
  } else {
    hipMemsetAsync(cnt, 0, sizeof(int)*kNN, stream);       // 40KB fill
  }
  // deg + x->fp16 cast fused (cast makes agg32 rows 64B = 1 line/gather)
  k_deg    <<<(kNE+255)/256, 256, 0, stream>>>(ei, pb, cnt, is64_host, x, xh);
  k_scan   <<<1, 1024, 0, stream>>>(cnt, offs, cur, dis);
  k_scatter<<<(kNE+255)/256, 256, 0, stream>>>(ei, pb, cur, dis, edat, is64_host);

  // GCN-0: aggregate 32-feat fp16 x (A_hat x), then MFMA GEMM (+gb0+relu)
  k_agg<kFIN, _Float16><<<(kNN/2*(kTT/4) + 3)/4, 256, 0, stream>>>(xh, aggX, dis, offs, edat);
  k_gemm_mfma<kFIN><<<(kNN*kTT + 127)/128, 256, 0, stream>>>(aggX, gw0, gb0, bufB);
  // GCN-1: aggregate 64-feat (half4, 3 edge-walk passes), MFMA GEMM (+gb1+relu)
  k_agg64<<<(kNN/2*(kTT/4)) / 4, 256, 0, stream>>>(bufB, bufA, dis, offs, edat);
  k_gemm_mfma<kHH><<<(kNN*kTT + 127)/128, 256, 0, stream>>>(bufA, gw1, gb1, bufB);

  // Fused 2-layer LSTM + FC -> out (three 16-node tiles per block, t-major x)
  k_rec2<<<(kNN + 16*kNU - 1)/(16*kNU), 512, 0, stream>>>(bufB, wih0, whh0, bih0, bhh0,
                                          wih1, whh1, bih1, bhh1, fcw, fcb, out);
}